// Round 1
// baseline (1057.042 us; speedup 1.0000x reference)
//
#include <hip/hip_runtime.h>
#include <stdint.h>

typedef unsigned short u16;
typedef short bf16x8 __attribute__((ext_vector_type(8)));
typedef float f32x4 __attribute__((ext_vector_type(4)));

#define NTOK 100352      // B*H*W tokens
#define NWIN 2048        // B * 64 windows
#define CC 256
#define NHEAD 8
#define HDIM 32
#define NWT 49           // tokens per window
#define MLPD 1024
#define ATT_SCALE 0.17677669529663687f  // 32^-0.5

__device__ __forceinline__ u16 f2b(float f) {
  union { float f; uint32_t u; } c; c.f = f;
  return (u16)((c.u + 0x7fffu + ((c.u >> 16) & 1u)) >> 16);
}
__device__ __forceinline__ float b2f(u16 h) {
  union { uint32_t u; float f; } c; c.u = ((uint32_t)h) << 16;
  return c.f;
}

__device__ __forceinline__ void gload_lds16(const void* g, void* l) {
  __builtin_amdgcn_global_load_lds((const __attribute__((address_space(1))) void*)g,
                                   (__attribute__((address_space(3))) void*)l, 16, 0, 0);
}

// ---------------- weight convert + transpose: w[K][N] fp32 -> wT[N][K] bf16
__global__ __launch_bounds__(256) void wconv_k(const float* __restrict__ w,
                                               u16* __restrict__ wT, int K, int N) {
  int i = blockIdx.x * 256 + threadIdx.x;
  if (i < K * N) {
    int k = i / N, n = i % N;
    wT[(size_t)n * K + k] = f2b(w[i]);
  }
}

// ---------------- LN (+ optional shift/window-partition) -> bf16 tokens
template<bool PART>
__global__ __launch_bounds__(256)
void ln_k(const float* __restrict__ x, const float* __restrict__ g,
          const float* __restrict__ be, u16* __restrict__ out) {
  int token = blockIdx.x * 4 + (threadIdx.x >> 6);
  int lane = threadIdx.x & 63;
  size_t src;
  if (PART) {
    int win = token / 49, nn = token % 49;
    int b = win >> 6, wh = (win >> 3) & 7, ww = win & 7;
    int i = nn / 7, j = nn % 7;
    int h = wh * 7 + i + 3; if (h >= 56) h -= 56;
    int w = ww * 7 + j + 3; if (w >= 56) w -= 56;
    src = ((size_t)((b * 56 + h) * 56 + w)) * CC;
  } else {
    src = (size_t)token * CC;
  }
  f32x4 v = *(const f32x4*)&x[src + lane * 4];
  float s1 = v[0] + v[1] + v[2] + v[3];
  float s2 = v[0]*v[0] + v[1]*v[1] + v[2]*v[2] + v[3]*v[3];
#pragma unroll
  for (int o = 32; o; o >>= 1) { s1 += __shfl_xor(s1, o); s2 += __shfl_xor(s2, o); }
  float mean = s1 * (1.f / 256.f);
  float var = s2 * (1.f / 256.f) - mean * mean;
  float rstd = rsqrtf(var + 1e-5f);
  f32x4 gv = *(const f32x4*)&g[lane * 4];
  f32x4 bv = *(const f32x4*)&be[lane * 4];
  float y0 = (v[0]-mean)*rstd*gv[0] + bv[0];
  float y1 = (v[1]-mean)*rstd*gv[1] + bv[1];
  float y2 = (v[2]-mean)*rstd*gv[2] + bv[2];
  float y3 = (v[3]-mean)*rstd*gv[3] + bv[3];
  uint32_t lo = f2b(y0) | ((uint32_t)f2b(y1) << 16);
  uint32_t hi = f2b(y2) | ((uint32_t)f2b(y3) << 16);
  *(uint2*)&out[(size_t)token * CC + lane * 4] = make_uint2(lo, hi);
}

// ---------------- GEMM: C = A(MxK,bf16) * BT(NxK,bf16)^T + bias, epilogue variants
#define BM 128
#define BN 128
#define BK 32
enum { EPI_QKV = 0, EPI_PROJ = 1, EPI_GELU = 2, EPI_FC2 = 3 };

template<int EPI>
__global__ __launch_bounds__(256)
void gemm_k(const u16* __restrict__ A, const u16* __restrict__ BT,
            const float* __restrict__ bias, int K,
            void* __restrict__ p0, const void* __restrict__ p1) {
  __shared__ u16 aL[BM * BK];
  __shared__ u16 bL[BN * BK];
  const int tid = threadIdx.x;
  const int lane = tid & 63;
  const int wv = tid >> 6;
  const int wm = wv >> 1, wn = wv & 1;
  const long m0 = (long)blockIdx.y * BM;
  const int n0 = blockIdx.x * BN;

  f32x4 acc[4][4] = {};

  const int r15 = lane & 15;
  const int kc = lane >> 4;
  const int rcsw = kc ^ ((r15 >> 1) & 3);   // swizzled 16B-chunk for ds_read

  // staging decomposition: slot = tid + 256*it; row = slot>>2, chunk c = slot&3
  // LDS kept LINEAR (global_load_lds requirement); global SOURCE pre-swizzled.
  for (int kt = 0; kt < K; kt += BK) {
#pragma unroll
    for (int it = 0; it < 2; ++it) {
      int slot = tid + 256 * it;
      int row = slot >> 2, c = slot & 3;
      int cs = c ^ ((row >> 1) & 3);
      gload_lds16(&A[(m0 + row) * K + kt + cs * 8], &aL[slot * 8]);
    }
#pragma unroll
    for (int it = 0; it < 2; ++it) {
      int slot = tid + 256 * it;
      int row = slot >> 2, c = slot & 3;
      int cs = c ^ ((row >> 1) & 3);
      gload_lds16(&BT[(size_t)(n0 + row) * K + kt + cs * 8], &bL[slot * 8]);
    }
    __syncthreads();   // compiler drains vmcnt before s_barrier
    bf16x8 af[4], bfr[4];
#pragma unroll
    for (int m = 0; m < 4; ++m)
      af[m] = *(const bf16x8*)&aL[(wm * 64 + m * 16 + r15) * BK + rcsw * 8];
#pragma unroll
    for (int n = 0; n < 4; ++n)
      bfr[n] = *(const bf16x8*)&bL[(wn * 64 + n * 16 + r15) * BK + rcsw * 8];
#pragma unroll
    for (int m = 0; m < 4; ++m)
#pragma unroll
      for (int n = 0; n < 4; ++n)
        acc[m][n] = __builtin_amdgcn_mfma_f32_16x16x32_bf16(af[m], bfr[n], acc[m][n], 0, 0, 0);
    __syncthreads();
  }

  // epilogue: C/D layout col = lane&15, row = (lane>>4)*4 + j   [m89-verified]
#pragma unroll
  for (int m = 0; m < 4; ++m) {
    int rb = wm * 64 + m * 16 + (lane >> 4) * 4;
#pragma unroll
    for (int n = 0; n < 4; ++n) {
      int col = n0 + wn * 64 + n * 16 + (lane & 15);
      float bv = bias[col];
#pragma unroll
      for (int j = 0; j < 4; ++j) {
        int grow = (int)m0 + rb + j;
        float v = acc[m][n][j] + bv;
        if (EPI == EPI_QKV) {
          v = fmaxf(v, 0.f);
          int win = grow / 49, nn = grow % 49;
          int s = col >> 8, head = (col >> 5) & 7, d = col & 31;
          u16* dst = (u16*)p0 + (size_t)s * ((size_t)NTOK * CC);
          dst[(((size_t)(win * NHEAD + head)) * NWT + nn) * HDIM + d] = f2b(v);
        } else if (EPI == EPI_PROJ) {
          int win = grow / 49, nn = grow % 49;
          int b = win >> 6, wh = (win >> 3) & 7, ww = win & 7;
          int i = nn / 7, jj = nn % 7;
          int h = wh * 7 + i + 3; if (h >= 56) h -= 56;
          int w = ww * 7 + jj + 3; if (w >= 56) w -= 56;
          size_t pix = (size_t)((b * 56 + h) * 56 + w);
          float o = ((const float*)p1)[pix * CC + col] + v;
          ((float*)p0)[pix * CC + col] = o;
        } else if (EPI == EPI_GELU) {
          float gl = 0.5f * v * (1.f + erff(v * 0.70710678118654752f));
          ((u16*)p0)[(size_t)grow * MLPD + col] = f2b(gl);
        } else {  // EPI_FC2
          float o = ((const float*)p1)[(size_t)grow * CC + col] + v;
          ((float*)p0)[(size_t)grow * CC + col] = o;
        }
      }
    }
  }
}

// ---------------- fused window attention: one block per (window, head)
__global__ __launch_bounds__(256)
void attn_k(const u16* __restrict__ q, const u16* __restrict__ k2,
            const u16* __restrict__ v2, const float* __restrict__ rpb,
            u16* __restrict__ out) {
  __shared__ float qs[NWT * 33], ks[NWT * 33], vs[NWT * 33], S[NWT * 50];
  const int tid = threadIdx.x;
  const int blk = blockIdx.x;
  const int head = blk & 7;
  const int win = blk >> 3;
  const int wimg = win & 63;
  const int wh = wimg >> 3, ww = wimg & 7;
  const size_t base = (size_t)blk * (NWT * HDIM);
  for (int idx = tid; idx < NWT * HDIM; idx += 256) {
    int n = idx >> 5, d = idx & 31;
    qs[n * 33 + d] = b2f(q[base + idx]);
    ks[n * 33 + d] = b2f(k2[base + idx]);
    vs[n * 33 + d] = b2f(v2[base + idx]);
  }
  __syncthreads();
  for (int idx = tid; idx < NWT * NWT; idx += 256) {
    int n = idx / 49, m = idx % 49;
    float s = 0.f;
#pragma unroll
    for (int d = 0; d < 32; ++d) s += qs[n * 33 + d] * ks[m * 33 + d];
    int i1 = n / 7, j1 = n % 7, i2 = m / 7, j2 = m % 7;
    s = s * ATT_SCALE + rpb[((i1 - i2 + 6) * 13 + (j1 - j2 + 6)) * 8 + head];
    int h1 = wh * 7 + i1, w1 = ww * 7 + j1, h2 = wh * 7 + i2, w2 = ww * 7 + j2;
    int L1 = (h1 < 49 ? 0 : (h1 < 53 ? 1 : 2)) * 3 + (w1 < 49 ? 0 : (w1 < 53 ? 1 : 2));
    int L2 = (h2 < 49 ? 0 : (h2 < 53 ? 1 : 2)) * 3 + (w2 < 49 ? 0 : (w2 < 53 ? 1 : 2));
    if (L1 != L2) s -= 1e9f;
    S[n * 50 + m] = fmaxf(s, 0.f);   // relu(attn + bias + mask)
  }
  __syncthreads();
  {
    int wvv = tid >> 6, ln = tid & 63;
    for (int row = wvv; row < NWT; row += 4) {
      float val = (ln < 49) ? S[row * 50 + ln] : -1e30f;
      float mx = val;
#pragma unroll
      for (int o = 32; o; o >>= 1) mx = fmaxf(mx, __shfl_xor(mx, o));
      float e = (ln < 49) ? __expf(val - mx) : 0.f;
      float sm = e;
#pragma unroll
      for (int o = 32; o; o >>= 1) sm += __shfl_xor(sm, o);
      if (ln < 49) S[row * 50 + ln] = e / sm;
    }
  }
  __syncthreads();
  for (int idx = tid; idx < NWT * HDIM; idx += 256) {
    int n = idx >> 5, d = idx & 31;
    float o = 0.f;
    for (int m = 0; m < 49; ++m) o += S[n * 50 + m] * vs[m * 33 + d];
    o = fmaxf(o, 0.f);
    out[((size_t)(win * 49 + n)) * CC + head * HDIM + d] = f2b(o);
  }
}

// ---------------- launch
extern "C" void kernel_launch(void* const* d_in, const int* in_sizes, int n_in,
                              void* d_out, int out_size, void* d_ws, size_t ws_size,
                              hipStream_t stream) {
  const float* x      = (const float*)d_in[0];
  const float* gamma1 = (const float*)d_in[1];
  const float* beta1  = (const float*)d_in[2];
  const float* w_qkv  = (const float*)d_in[3];
  const float* b_qkv  = (const float*)d_in[4];
  const float* rpb    = (const float*)d_in[5];
  const float* w_proj = (const float*)d_in[6];
  const float* b_proj = (const float*)d_in[7];
  const float* gamma2 = (const float*)d_in[8];
  const float* beta2  = (const float*)d_in[9];
  const float* w_fc1  = (const float*)d_in[10];
  const float* b_fc1  = (const float*)d_in[11];
  const float* w_fc2  = (const float*)d_in[12];
  const float* b_fc2  = (const float*)d_in[13];
  float* out = (float*)d_out;

  char* ws = (char*)d_ws;
  size_t off = 0;
  auto alloc = [&](size_t bytes) { void* p = ws + off; off = (off + bytes + 255) & ~(size_t)255; return p; };

  u16* wqkvT = (u16*)alloc(768 * 256 * 2);
  u16* wprojT = (u16*)alloc(256 * 256 * 2);
  u16* wfc1T = (u16*)alloc(1024 * 256 * 2);
  u16* wfc2T = (u16*)alloc(256 * 1024 * 2);
  // region2: xw -> attn_out -> xn2 (lifetimes disjoint)
  u16* region2 = (u16*)alloc((size_t)NTOK * CC * 2);
  // region1: q|k|v (3x 51.4MB); after attention reused as x2 (fp32, 102.8MB) + h chunk
  char* region1 = (char*)alloc((size_t)3 * NTOK * CC * 2);

  u16* xw = region2;
  u16* qb = (u16*)region1;
  u16* kb = qb + (size_t)NTOK * CC;
  u16* vb = kb + (size_t)NTOK * CC;
  u16* attn_out = region2;
  float* x2 = (float*)region1;
  u16* xn2 = region2;
  u16* hbuf = (u16*)(region1 + (size_t)NTOK * CC * 4);  // after x2's 102.8MB

  if (ws_size < off) return;  // insufficient scratch: fail visibly

  wconv_k<<<(256 * 768 + 255) / 256, 256, 0, stream>>>(w_qkv, wqkvT, 256, 768);
  wconv_k<<<(256 * 256 + 255) / 256, 256, 0, stream>>>(w_proj, wprojT, 256, 256);
  wconv_k<<<(256 * 1024 + 255) / 256, 256, 0, stream>>>(w_fc1, wfc1T, 256, 1024);
  wconv_k<<<(1024 * 256 + 255) / 256, 256, 0, stream>>>(w_fc2, wfc2T, 1024, 256);

  // LN1 + shift + partition
  ln_k<true><<<NTOK / 4, 256, 0, stream>>>(x, gamma1, beta1, xw);

  // QKV GEMM: M=100352, N=768, K=256
  gemm_k<EPI_QKV><<<dim3(768 / BN, NTOK / BM), 256, 0, stream>>>(
      xw, wqkvT, b_qkv, 256, (void*)qb, nullptr);

  // fused window attention
  attn_k<<<NWIN * NHEAD, 256, 0, stream>>>(qb, kb, vb, rpb, attn_out);

  // proj GEMM + reverse shift + residual: M=100352, N=256, K=256
  gemm_k<EPI_PROJ><<<dim3(256 / BN, NTOK / BM), 256, 0, stream>>>(
      attn_out, wprojT, b_proj, 256, (void*)x2, (const void*)x);

  // LN2
  ln_k<false><<<NTOK / 4, 256, 0, stream>>>(x2, gamma2, beta2, xn2);

  // MLP in 8 M-chunks of 12544 rows (h buffer 25.7MB)
  const int MCH = 12544;
  for (int c = 0; c < 8; ++c) {
    const u16* a1 = xn2 + (size_t)c * MCH * CC;
    gemm_k<EPI_GELU><<<dim3(MLPD / BN, MCH / BM), 256, 0, stream>>>(
        a1, wfc1T, b_fc1, 256, (void*)hbuf, nullptr);
    gemm_k<EPI_FC2><<<dim3(CC / BN, MCH / BM), 256, 0, stream>>>(
        hbuf, wfc2T, b_fc2, 1024, (void*)(out + (size_t)c * MCH * CC),
        (const void*)(x2 + (size_t)c * MCH * CC));
  }
}

// Round 2
// 734.215 us; speedup vs baseline: 1.4397x; 1.4397x over previous
//
#include <hip/hip_runtime.h>
#include <stdint.h>

typedef unsigned short u16;
typedef short bf16x8 __attribute__((ext_vector_type(8)));
typedef float f32x4 __attribute__((ext_vector_type(4)));

#define NTOK 100352      // B*H*W tokens
#define NWIN 2048        // B * 64 windows
#define CC 256
#define NHEAD 8
#define HDIM 32
#define NWT 49           // tokens per window
#define MLPD 1024
#define ATT_SCALE 0.17677669529663687f  // 32^-0.5

__device__ __forceinline__ u16 f2b(float f) {
  union { float f; uint32_t u; } c; c.f = f;
  return (u16)((c.u + 0x7fffu + ((c.u >> 16) & 1u)) >> 16);
}
__device__ __forceinline__ float b2f(u16 h) {
  union { uint32_t u; float f; } c; c.u = ((uint32_t)h) << 16;
  return c.f;
}

__device__ __forceinline__ void gload_lds16(const void* g, void* l) {
  __builtin_amdgcn_global_load_lds((const __attribute__((address_space(1))) void*)g,
                                   (__attribute__((address_space(3))) void*)l, 16, 0, 0);
}

// ---------------- weight convert + transpose: w[K][N] fp32 -> wT[N][K] bf16
__global__ __launch_bounds__(256) void wconv_k(const float* __restrict__ w,
                                               u16* __restrict__ wT, int K, int N) {
  int i = blockIdx.x * 256 + threadIdx.x;
  if (i < K * N) {
    int k = i / N, n = i % N;
    wT[(size_t)n * K + k] = f2b(w[i]);
  }
}

// ---------------- relative-position bias LUT: lut[h][m][n] (64x64 padded, 0 outside 49)
__global__ __launch_bounds__(256) void bias_lut_k(const float* __restrict__ rpb,
                                                  float* __restrict__ lut) {
  int i = blockIdx.x * 256 + threadIdx.x;
  if (i >= 8 * 64 * 64) return;
  int h = i >> 12, m = (i >> 6) & 63, n = i & 63;
  float v = 0.f;
  if (m < 49 && n < 49) {
    int i1 = n / 7, j1 = n % 7;   // query coords
    int i2 = m / 7, j2 = m % 7;   // key coords
    v = rpb[((i1 - i2 + 6) * 13 + (j1 - j2 + 6)) * 8 + h];
  }
  lut[i] = v;
}

// ---------------- LN (+ optional shift/window-partition) -> bf16 tokens
template<bool PART>
__global__ __launch_bounds__(256)
void ln_k(const float* __restrict__ x, const float* __restrict__ g,
          const float* __restrict__ be, u16* __restrict__ out) {
  int token = blockIdx.x * 4 + (threadIdx.x >> 6);
  int lane = threadIdx.x & 63;
  size_t src;
  if (PART) {
    int win = token / 49, nn = token % 49;
    int b = win >> 6, wh = (win >> 3) & 7, ww = win & 7;
    int i = nn / 7, j = nn % 7;
    int h = wh * 7 + i + 3; if (h >= 56) h -= 56;
    int w = ww * 7 + j + 3; if (w >= 56) w -= 56;
    src = ((size_t)((b * 56 + h) * 56 + w)) * CC;
  } else {
    src = (size_t)token * CC;
  }
  f32x4 v = *(const f32x4*)&x[src + lane * 4];
  float s1 = v[0] + v[1] + v[2] + v[3];
  float s2 = v[0]*v[0] + v[1]*v[1] + v[2]*v[2] + v[3]*v[3];
#pragma unroll
  for (int o = 32; o; o >>= 1) { s1 += __shfl_xor(s1, o); s2 += __shfl_xor(s2, o); }
  float mean = s1 * (1.f / 256.f);
  float var = s2 * (1.f / 256.f) - mean * mean;
  float rstd = rsqrtf(var + 1e-5f);
  f32x4 gv = *(const f32x4*)&g[lane * 4];
  f32x4 bv = *(const f32x4*)&be[lane * 4];
  float y0 = (v[0]-mean)*rstd*gv[0] + bv[0];
  float y1 = (v[1]-mean)*rstd*gv[1] + bv[1];
  float y2 = (v[2]-mean)*rstd*gv[2] + bv[2];
  float y3 = (v[3]-mean)*rstd*gv[3] + bv[3];
  uint32_t lo = f2b(y0) | ((uint32_t)f2b(y1) << 16);
  uint32_t hi = f2b(y2) | ((uint32_t)f2b(y3) << 16);
  *(uint2*)&out[(size_t)token * CC + lane * 4] = make_uint2(lo, hi);
}

// ---------------- GEMM: C = A(MxK,bf16) * BT(NxK,bf16)^T + bias, epilogue variants
#define BM 128
#define BN 128
#define BK 32
enum { EPI_QKV = 0, EPI_PROJ = 1, EPI_GELU = 2, EPI_FC2 = 3 };

template<int EPI>
__global__ __launch_bounds__(256)
void gemm_k(const u16* __restrict__ A, const u16* __restrict__ BT,
            const float* __restrict__ bias, int K,
            void* __restrict__ p0, const void* __restrict__ p1) {
  __shared__ u16 aL[BM * BK];
  __shared__ u16 bL[BN * BK];
  const int tid = threadIdx.x;
  const int lane = tid & 63;
  const int wv = tid >> 6;
  const int wm = wv >> 1, wn = wv & 1;
  const long m0 = (long)blockIdx.y * BM;
  const int n0 = blockIdx.x * BN;

  f32x4 acc[4][4] = {};

  const int r15 = lane & 15;
  const int kc = lane >> 4;
  const int rcsw = kc ^ ((r15 >> 1) & 3);   // swizzled 16B-chunk for ds_read

  for (int kt = 0; kt < K; kt += BK) {
#pragma unroll
    for (int it = 0; it < 2; ++it) {
      int slot = tid + 256 * it;
      int row = slot >> 2, c = slot & 3;
      int cs = c ^ ((row >> 1) & 3);
      gload_lds16(&A[(m0 + row) * K + kt + cs * 8], &aL[slot * 8]);
    }
#pragma unroll
    for (int it = 0; it < 2; ++it) {
      int slot = tid + 256 * it;
      int row = slot >> 2, c = slot & 3;
      int cs = c ^ ((row >> 1) & 3);
      gload_lds16(&BT[(size_t)(n0 + row) * K + kt + cs * 8], &bL[slot * 8]);
    }
    __syncthreads();
    bf16x8 af[4], bfr[4];
#pragma unroll
    for (int m = 0; m < 4; ++m)
      af[m] = *(const bf16x8*)&aL[(wm * 64 + m * 16 + r15) * BK + rcsw * 8];
#pragma unroll
    for (int n = 0; n < 4; ++n)
      bfr[n] = *(const bf16x8*)&bL[(wn * 64 + n * 16 + r15) * BK + rcsw * 8];
#pragma unroll
    for (int m = 0; m < 4; ++m)
#pragma unroll
      for (int n = 0; n < 4; ++n)
        acc[m][n] = __builtin_amdgcn_mfma_f32_16x16x32_bf16(af[m], bfr[n], acc[m][n], 0, 0, 0);
    __syncthreads();
  }

  // epilogue: C/D layout col = lane&15, row = (lane>>4)*4 + j
#pragma unroll
  for (int m = 0; m < 4; ++m) {
    int rb = wm * 64 + m * 16 + (lane >> 4) * 4;
#pragma unroll
    for (int n = 0; n < 4; ++n) {
      int col = n0 + wn * 64 + n * 16 + (lane & 15);
      float bv = bias[col];
#pragma unroll
      for (int j = 0; j < 4; ++j) {
        int grow = (int)m0 + rb + j;
        float v = acc[m][n][j] + bv;
        if (EPI == EPI_QKV) {
          v = fmaxf(v, 0.f);
          int s = col >> 8, head = (col >> 5) & 7, d = col & 31;
          if (s == 0) v *= ATT_SCALE;   // fold softmax scale into q
          int win = grow / 49, nn = grow % 49;
          u16* dst = (u16*)p0 + (size_t)s * ((size_t)NTOK * CC);
          dst[(((size_t)(win * NHEAD + head)) * NWT + nn) * HDIM + d] = f2b(v);
        } else if (EPI == EPI_PROJ) {
          int win = grow / 49, nn = grow % 49;
          int b = win >> 6, wh = (win >> 3) & 7, ww = win & 7;
          int i = nn / 7, jj = nn % 7;
          int h = wh * 7 + i + 3; if (h >= 56) h -= 56;
          int w = ww * 7 + jj + 3; if (w >= 56) w -= 56;
          size_t pix = (size_t)((b * 56 + h) * 56 + w);
          float o = ((const float*)p1)[pix * CC + col] + v;
          ((float*)p0)[pix * CC + col] = o;
        } else if (EPI == EPI_GELU) {
          float gl = 0.5f * v * (1.f + erff(v * 0.70710678118654752f));
          ((u16*)p0)[(size_t)grow * MLPD + col] = f2b(gl);
        } else {  // EPI_FC2
          float o = ((const float*)p1)[(size_t)grow * CC + col] + v;
          ((float*)p0)[(size_t)grow * CC + col] = o;
        }
      }
    }
  }
}

// ---------------- MFMA window attention: 1 wave = 1 (window, head), 4 waves/block
// T = K*Q^T via mfma_16x16x32 (key index m in registers, query n in lanes);
// wave-parallel softmax over m; P -> LDS (b64 packed writes, ldp=72, bank-balanced);
// PV: A=P from LDS (ds_read_b128), B=V direct from global.
__global__ __launch_bounds__(256)
void attn_mfma_k(const u16* __restrict__ q, const u16* __restrict__ k2,
                 const u16* __restrict__ v2, const float* __restrict__ lut,
                 u16* __restrict__ out) {
  __shared__ u16 P_lds[4][64 * 72];
  const int tid = threadIdx.x;
  const int wv = tid >> 6;
  const int lane = tid & 63;
  const int c = lane & 15;
  const int g = lane >> 4;
  const int blk = blockIdx.x * 4 + wv;   // (window, head) id
  const int head = blk & 7;
  const int win = blk >> 3;
  const int wimg = win & 63;
  const int wh = wimg >> 3, ww = wimg & 7;
  const size_t base = (size_t)blk * (NWT * HDIM);
  u16* Pw = P_lds[wv];

  // ---- fragment loads (Q scaled at QKV epilogue)
  bf16x8 kf[4], qf[4];
#pragma unroll
  for (int t = 0; t < 4; ++t) {
    kf[t] = *(const bf16x8*)&k2[base + (size_t)(t * 16 + c) * HDIM + g * 8];
    qf[t] = *(const bf16x8*)&q [base + (size_t)(t * 16 + c) * HDIM + g * 8];
  }
  // V B-fragments early (latency hidden under QK^T+softmax): col d=td*16+c, k m=kc*32+g*8+jj
  bf16x8 vf[2][2];
#pragma unroll
  for (int kcc = 0; kcc < 2; ++kcc)
#pragma unroll
    for (int td = 0; td < 2; ++td)
#pragma unroll
      for (int jj = 0; jj < 8; ++jj) {
        int m = kcc * 32 + g * 8 + jj;
        m = m < 49 ? m : 48;   // clamp: avoids NaN garbage; P there is exactly 0
        vf[kcc][td][jj] = (short)v2[base + (size_t)m * HDIM + td * 16 + c];
      }

  // ---- T = K·Q^T  (T[m][n]; m = tm*16+g*4+j in regs, n = tn*16+c in lanes)
  f32x4 acc[4][4] = {};
#pragma unroll
  for (int tm = 0; tm < 4; ++tm)
#pragma unroll
    for (int tn = 0; tn < 4; ++tn)
      acc[tm][tn] = __builtin_amdgcn_mfma_f32_16x16x32_bf16(kf[tm], qf[tn], acc[tm][tn], 0, 0, 0);

  // ---- bias + shifted-window mask + relu (masked -> 0, still in softmax sum)
  const float* lrow = &lut[(size_t)head * 64 * 64];
  int Ln[4];
#pragma unroll
  for (int tn = 0; tn < 4; ++tn) {
    int n = tn * 16 + c;
    int i1 = (n * 9363) >> 16;          // n/7 for n<64
    int j1 = n - i1 * 7;
    int rh = (wh < 7) ? 0 : (i1 < 4 ? 1 : 2);
    int rw = (ww < 7) ? 0 : (j1 < 4 ? 1 : 2);
    Ln[tn] = rh * 3 + rw;
  }
  float colmax[4] = {0.f, 0.f, 0.f, 0.f};   // relu => max >= 0
#pragma unroll
  for (int tm = 0; tm < 4; ++tm)
#pragma unroll
    for (int j = 0; j < 4; ++j) {
      int m = tm * 16 + g * 4 + j;
      int i2 = (m * 9363) >> 16;
      int j2 = m - i2 * 7;
      int rh = (wh < 7) ? 0 : (i2 < 4 ? 1 : 2);
      int rw = (ww < 7) ? 0 : (j2 < 4 ? 1 : 2);
      int Lm = rh * 3 + rw;
#pragma unroll
      for (int tn = 0; tn < 4; ++tn) {
        float s = acc[tm][tn][j] + lrow[m * 64 + tn * 16 + c];
        s = fmaxf(s, 0.f);
        if (Lm != Ln[tn]) s = 0.f;      // mask: relu(-1e9+x)=0 (interior windows: all labels 0)
        acc[tm][tn][j] = s;
        colmax[tn] = fmaxf(colmax[tn], s);
      }
    }
#pragma unroll
  for (int tn = 0; tn < 4; ++tn) {
    colmax[tn] = fmaxf(colmax[tn], __shfl_xor(colmax[tn], 16));
    colmax[tn] = fmaxf(colmax[tn], __shfl_xor(colmax[tn], 32));
  }
  float colsum[4] = {0.f, 0.f, 0.f, 0.f};
#pragma unroll
  for (int tm = 0; tm < 4; ++tm)
#pragma unroll
    for (int j = 0; j < 4; ++j) {
      int m = tm * 16 + g * 4 + j;
      bool mvalid = (m < NWT);
#pragma unroll
      for (int tn = 0; tn < 4; ++tn) {
        float e = mvalid ? __expf(acc[tm][tn][j] - colmax[tn]) : 0.f;
        acc[tm][tn][j] = e;
        colsum[tn] += e;
      }
    }
#pragma unroll
  for (int tn = 0; tn < 4; ++tn) {
    colsum[tn] += __shfl_xor(colsum[tn], 16);
    colsum[tn] += __shfl_xor(colsum[tn], 32);
    colsum[tn] = 1.f / colsum[tn];
  }

  // ---- P -> LDS row-major [n][m], ldp=72 (b64 writes, j-consecutive m)
#pragma unroll
  for (int tn = 0; tn < 4; ++tn) {
    int n = tn * 16 + c;
#pragma unroll
    for (int tm = 0; tm < 4; ++tm) {
      float r = colsum[tn];
      uint32_t w0 = (uint32_t)f2b(acc[tm][tn][0] * r) | ((uint32_t)f2b(acc[tm][tn][1] * r) << 16);
      uint32_t w1 = (uint32_t)f2b(acc[tm][tn][2] * r) | ((uint32_t)f2b(acc[tm][tn][3] * r) << 16);
      *(uint2*)&Pw[n * 72 + tm * 16 + g * 4] = make_uint2(w0, w1);
    }
  }

  // ---- out = P·V  (A=P rows from LDS, B=V regs); out[n][d]
  f32x4 oacc[4][2] = {};
#pragma unroll
  for (int kcc = 0; kcc < 2; ++kcc) {
    bf16x8 pf[4];
#pragma unroll
    for (int tr = 0; tr < 4; ++tr)
      pf[tr] = *(const bf16x8*)&Pw[(tr * 16 + c) * 72 + kcc * 32 + g * 8];
#pragma unroll
    for (int tr = 0; tr < 4; ++tr)
#pragma unroll
      for (int td = 0; td < 2; ++td)
        oacc[tr][td] = __builtin_amdgcn_mfma_f32_16x16x32_bf16(pf[tr], vf[kcc][td], oacc[tr][td], 0, 0, 0);
  }

  // ---- relu + store (rows n<49 only)
#pragma unroll
  for (int tr = 0; tr < 4; ++tr)
#pragma unroll
    for (int j = 0; j < 4; ++j) {
      int n = tr * 16 + g * 4 + j;
      if (n < NWT) {
#pragma unroll
        for (int td = 0; td < 2; ++td) {
          int d = td * 16 + c;
          out[((size_t)(win * NWT + n)) * CC + head * HDIM + d] =
              f2b(fmaxf(oacc[tr][td][j], 0.f));
        }
      }
    }
}

// ---------------- launch
extern "C" void kernel_launch(void* const* d_in, const int* in_sizes, int n_in,
                              void* d_out, int out_size, void* d_ws, size_t ws_size,
                              hipStream_t stream) {
  const float* x      = (const float*)d_in[0];
  const float* gamma1 = (const float*)d_in[1];
  const float* beta1  = (const float*)d_in[2];
  const float* w_qkv  = (const float*)d_in[3];
  const float* b_qkv  = (const float*)d_in[4];
  const float* rpb    = (const float*)d_in[5];
  const float* w_proj = (const float*)d_in[6];
  const float* b_proj = (const float*)d_in[7];
  const float* gamma2 = (const float*)d_in[8];
  const float* beta2  = (const float*)d_in[9];
  const float* w_fc1  = (const float*)d_in[10];
  const float* b_fc1  = (const float*)d_in[11];
  const float* w_fc2  = (const float*)d_in[12];
  const float* b_fc2  = (const float*)d_in[13];
  float* out = (float*)d_out;

  char* ws = (char*)d_ws;
  size_t off = 0;
  auto alloc = [&](size_t bytes) { void* p = ws + off; off = (off + bytes + 255) & ~(size_t)255; return p; };

  u16* wqkvT = (u16*)alloc(768 * 256 * 2);
  u16* wprojT = (u16*)alloc(256 * 256 * 2);
  u16* wfc1T = (u16*)alloc(1024 * 256 * 2);
  u16* wfc2T = (u16*)alloc(256 * 1024 * 2);
  float* lut = (float*)alloc(8 * 64 * 64 * 4);
  // region2: xw -> attn_out -> xn2 (lifetimes disjoint)
  u16* region2 = (u16*)alloc((size_t)NTOK * CC * 2);
  // region1: q|k|v (3x 51.4MB); after attention reused as x2 (fp32, 102.8MB) + h chunk
  char* region1 = (char*)alloc((size_t)3 * NTOK * CC * 2);

  u16* xw = region2;
  u16* qb = (u16*)region1;
  u16* kb = qb + (size_t)NTOK * CC;
  u16* vb = kb + (size_t)NTOK * CC;
  u16* attn_out = region2;
  float* x2 = (float*)region1;
  u16* xn2 = region2;
  u16* hbuf = (u16*)(region1 + (size_t)NTOK * CC * 4);  // after x2's 102.8MB

  if (ws_size < off) return;  // insufficient scratch: fail visibly

  wconv_k<<<(256 * 768 + 255) / 256, 256, 0, stream>>>(w_qkv, wqkvT, 256, 768);
  wconv_k<<<(256 * 256 + 255) / 256, 256, 0, stream>>>(w_proj, wprojT, 256, 256);
  wconv_k<<<(256 * 1024 + 255) / 256, 256, 0, stream>>>(w_fc1, wfc1T, 256, 1024);
  wconv_k<<<(1024 * 256 + 255) / 256, 256, 0, stream>>>(w_fc2, wfc2T, 1024, 256);
  bias_lut_k<<<(8 * 64 * 64) / 256, 256, 0, stream>>>(rpb, lut);

  // LN1 + shift + partition
  ln_k<true><<<NTOK / 4, 256, 0, stream>>>(x, gamma1, beta1, xw);

  // QKV GEMM: M=100352, N=768, K=256
  gemm_k<EPI_QKV><<<dim3(768 / BN, NTOK / BM), 256, 0, stream>>>(
      xw, wqkvT, b_qkv, 256, (void*)qb, nullptr);

  // fused MFMA window attention: 1 wave per (window, head)
  attn_mfma_k<<<NWIN * NHEAD / 4, 256, 0, stream>>>(qb, kb, vb, lut, attn_out);

  // proj GEMM + reverse shift + residual: M=100352, N=256, K=256
  gemm_k<EPI_PROJ><<<dim3(256 / BN, NTOK / BM), 256, 0, stream>>>(
      attn_out, wprojT, b_proj, 256, (void*)x2, (const void*)x);

  // LN2
  ln_k<false><<<NTOK / 4, 256, 0, stream>>>(x2, gamma2, beta2, xn2);

  // MLP in 8 M-chunks of 12544 rows (h buffer 25.7MB)
  const int MCH = 12544;
  for (int c = 0; c < 8; ++c) {
    const u16* a1 = xn2 + (size_t)c * MCH * CC;
    gemm_k<EPI_GELU><<<dim3(MLPD / BN, MCH / BM), 256, 0, stream>>>(
        a1, wfc1T, b_fc1, 256, (void*)hbuf, nullptr);
    gemm_k<EPI_FC2><<<dim3(CC / BN, MCH / BM), 256, 0, stream>>>(
        hbuf, wfc2T, b_fc2, 1024, (void*)(out + (size_t)c * MCH * CC),
        (const void*)(x2 + (size_t)c * MCH * CC));
  }
}